// Round 7
// baseline (1440.761 us; speedup 1.0000x reference)
//
#include <hip/hip_runtime.h>

// VectorQuantizer: z [16,4096,256] f32, emb [1024,256] f32.
// out = [ z_q (16777216 f32) | loss (1) | indices-as-f32 (65536) ]
//
// The harness's np reference computes dist = ||x||^2 - 2 x@emb.T + ||e||^2 in
// FLOAT32 (magnitude ~256, ulp 3e-5) then argmin with first-min tie-break.
// We replicate that chain bit-for-bit (modulo BLAS last-ulp in the dot):
//   g32 = f32(f64 dot);  t = fadd_rn(fsub_rn(sx32, 2*g32), se32[k])
// with sx32/se32 via numpy's exact pairwise-sum tree (no FMA contraction).

constexpr int D      = 256;
constexpr int KC     = 1024;
constexpr int BM     = 64;
constexpr int BN     = 64;
constexpr int NROWS  = 16 * 4096;                 // 65536
constexpr long long ZQ_N = (long long)NROWS * D;  // 16777216

// numpy pairwise sum of squares, 128 elements, stride s: 8 accumulators over
// stride-8 groups, 15 sequential adds each, then the fixed combine tree.
__device__ __forceinline__ float np_half_sumsq(const float* a, int s) {
    float r[8];
#pragma unroll
    for (int j = 0; j < 8; ++j) r[j] = __fmul_rn(a[j * s], a[j * s]);
    for (int i = 8; i < 128; i += 8)
#pragma unroll
        for (int j = 0; j < 8; ++j)
            r[j] = __fadd_rn(r[j], __fmul_rn(a[(i + j) * s], a[(i + j) * s]));
    return __fadd_rn(__fadd_rn(__fadd_rn(r[0], r[1]), __fadd_rn(r[2], r[3])),
                     __fadd_rn(__fadd_rn(r[4], r[5]), __fadd_rn(r[6], r[7])));
}
__device__ __forceinline__ float np_sumsq_256(const float* a, int s) {
    return __fadd_rn(np_half_sumsq(a, s), np_half_sumsq(a + 128 * s, s));
}

// ---------------------------------------------------------------- prep ----
// se32[k] = np-f32 sum(emb_k^2); zero the loss accumulator.
__global__ __launch_bounds__(256) void vq_prep(const float* __restrict__ emb,
                                               float* __restrict__ se32,
                                               double* __restrict__ acc) {
    int k = blockIdx.x * 256 + threadIdx.x;   // 4 blocks x 256
    if (k < KC) se32[k] = np_sumsq_256(emb + (size_t)k * D, 1);
    if (k == 0) *acc = 0.0;
}

// ---------------------------------------------------------------- main ----
__global__ __launch_bounds__(256) void vq_main(const float* __restrict__ z,
                                               const float* __restrict__ emb,
                                               const float* __restrict__ se32,
                                               float* __restrict__ out_zq,
                                               float* __restrict__ out_idx1,
                                               float* __restrict__ out_idx2,
                                               double* __restrict__ acc) {
    __shared__ float xs[D][BM];        // 64 KB, [d][row]
    __shared__ float es[32][BN];       // 8 KB  (reused for reduce)
    __shared__ float sxs[BM];
    __shared__ int   code_of_row[BM];
    __shared__ float wave_part[4];

    const int tid = threadIdx.x;
    const int tx  = tid & 15;          // code group
    const int ty  = tid >> 4;          // row group
    const int r0  = blockIdx.x * BM;

    {   // stage z rows into LDS, transposed
        int r = tid >> 2;
        int dbase = (tid & 3) << 6;
        const float* zp = z + (size_t)(r0 + r) * D + dbase;
#pragma unroll
        for (int j = 0; j < 16; ++j) {
            float4 v = *(const float4*)(zp + 4 * j);
            int d = dbase + 4 * j;
            xs[d + 0][r] = v.x; xs[d + 1][r] = v.y;
            xs[d + 2][r] = v.z; xs[d + 3][r] = v.w;
        }
    }
    __syncthreads();
    if (tid < BM) sxs[tid] = np_sumsq_256(&xs[0][tid], BM);  // np-f32 ||x||^2

    float bestv[4];
    int   bestk[4];
#pragma unroll
    for (int i = 0; i < 4; ++i) { bestv[i] = 3.0e38f; bestk[i] = 0; }

    for (int kt = 0; kt < KC / BN; ++kt) {
        const int k0 = kt * BN;
        double a[4][4];
#pragma unroll
        for (int i = 0; i < 4; ++i)
#pragma unroll
            for (int j = 0; j < 4; ++j) a[i][j] = 0.0;

        for (int dc = 0; dc < D / 32; ++dc) {
            const int d0 = dc * 32;
            __syncthreads();               // previous es readers done (also sxs)
            {   // stage emb tile (64 codes x 32 dims), transposed
                int c  = tid >> 2;
                int dd = (tid & 3) << 3;
                const float* ep = emb + (size_t)(k0 + c) * D + d0 + dd;
                float4 v0 = *(const float4*)(ep);
                float4 v1 = *(const float4*)(ep + 4);
                es[dd + 0][c] = v0.x; es[dd + 1][c] = v0.y;
                es[dd + 2][c] = v0.z; es[dd + 3][c] = v0.w;
                es[dd + 4][c] = v1.x; es[dd + 5][c] = v1.y;
                es[dd + 6][c] = v1.z; es[dd + 7][c] = v1.w;
            }
            __syncthreads();
#pragma unroll
            for (int kk = 0; kk < 32; ++kk) {
                float4 xv = *(const float4*)&xs[d0 + kk][ty << 2];
                float4 ev = *(const float4*)&es[kk][tx << 2];
                double xd[4] = { xv.x, xv.y, xv.z, xv.w };
                double ed[4] = { ev.x, ev.y, ev.z, ev.w };
#pragma unroll
                for (int i = 0; i < 4; ++i)
#pragma unroll
                    for (int j = 0; j < 4; ++j)
                        a[i][j] = __fma_rn(xd[i], ed[j], a[i][j]);
            }
        }
        // replicate np f32 chain: (sx - 2*g32) + se32[k]; first-min tie-break
#pragma unroll
        for (int j = 0; j < 4; ++j) {
            int k = k0 + (tx << 2) + j;
            float se = se32[k];
#pragma unroll
            for (int i = 0; i < 4; ++i) {
                float sx  = sxs[(ty << 2) + i];
                float g32 = (float)a[i][j];
                float t   = __fadd_rn(__fsub_rn(sx, 2.0f * g32), se);
                if (t < bestv[i]) { bestv[i] = t; bestk[i] = k; }  // k ascending
            }
        }
    }

    // ---- cross-thread argmin reduce (16 candidates per row) ----
    __syncthreads();
    float* red_val = &es[0][0];            // 1024 floats
    int*   red_idx = (int*)&es[16][0];     // 1024 ints
#pragma unroll
    for (int i = 0; i < 4; ++i) {
        int r = (ty << 2) + i;
        red_val[r * 16 + tx] = bestv[i];
        red_idx[r * 16 + tx] = bestk[i];
    }
    __syncthreads();
    if (tid < BM) {
        int r = tid;
        float bv = 3.0e38f; int bk = 1 << 30;
#pragma unroll
        for (int t = 0; t < 16; ++t) {
            float v  = red_val[r * 16 + t];
            int   id = red_idx[r * 16 + t];
            if (v < bv || (v == bv && id < bk)) { bv = v; bk = id; }
        }
        code_of_row[r] = bk;
        out_idx1[r0 + r] = (float)bk;
        out_idx2[r0 + r] = (float)bk;
    }
    __syncthreads();

    // ---- gather z_q, write out, accumulate loss ----
    float ls = 0.f;
    {
        int r = tid >> 2;
        int dbase = (tid & 3) << 6;
        int c = code_of_row[r];
        const float* ep = emb + (size_t)c * D + dbase;
        float* op = out_zq + (size_t)(r0 + r) * D + dbase;
#pragma unroll
        for (int j = 0; j < 16; ++j) {
            float4 e4 = *(const float4*)(ep + 4 * j);
            int d = dbase + 4 * j;
            float d0v = e4.x - xs[d + 0][r];
            float d1v = e4.y - xs[d + 1][r];
            float d2v = e4.z - xs[d + 2][r];
            float d3v = e4.w - xs[d + 3][r];
            ls += d0v * d0v + d1v * d1v + d2v * d2v + d3v * d3v;
            *(float4*)(op + 4 * j) = e4;
        }
    }
#pragma unroll
    for (int off = 32; off > 0; off >>= 1) ls += __shfl_down(ls, off);
    if ((tid & 63) == 0) wave_part[tid >> 6] = ls;
    __syncthreads();
    if (tid == 0) {
        double t = (double)wave_part[0] + (double)wave_part[1]
                 + (double)wave_part[2] + (double)wave_part[3];
        atomicAdd(acc, t);
    }
}

// ------------------------------------------------------------ finalize ----
__global__ void vq_finalize(const double* __restrict__ acc,
                            float* __restrict__ l1, float* __restrict__ l2) {
    double m = *acc / (double)ZQ_N;
    float v = (float)(1.25 * m);   // codebook + 0.25 * commitment (equal means)
    *l1 = v; *l2 = v;
}

// -------------------------------------------------------------- launch ----
extern "C" void kernel_launch(void* const* d_in, const int* in_sizes, int n_in,
                              void* d_out, int out_size, void* d_ws, size_t ws_size,
                              hipStream_t stream) {
    const float* z   = (const float*)d_in[0];
    const float* emb = (const float*)d_in[1];
    float* out = (float*)d_out;

    float* out_zq    = out;
    float* out_loss1 = out + ZQ_N;                       // dense layout (proven)
    float* out_idx1  = out + ZQ_N + 1;
    size_t osz = (size_t)out_size;
    float* out_idx2  = out + (osz - (size_t)NROWS);      // == out_idx1 when dense
    float* out_loss2 = out + (osz - (size_t)NROWS - 1);

    float*  se32 = (float*)d_ws;                         // 4 KB
    double* acc  = (double*)((char*)d_ws + 4096);        // 8 B

    vq_prep<<<4, 256, 0, stream>>>(emb, se32, acc);
    vq_main<<<NROWS / BM, 256, 0, stream>>>(z, emb, se32, out_zq, out_idx1,
                                            out_idx2, acc);
    vq_finalize<<<1, 1, 0, stream>>>(acc, out_loss1, out_loss2);
}